// Round 1
// baseline (11994.053 us; speedup 1.0000x reference)
//
#include <hip/hip_runtime.h>
#include <math.h>

#define B 16
#define S 511
#define F 128
#define D 512
#define H 8
#define NB 6
#define DH 64
#define MLPD 2048
#define T 512
#define EPS 1e-5f

// ---------------- embed: x = concat(cls, src@emb_W+emb_b) + pos ----------------
__global__ void embed_kernel(const float* __restrict__ src,
                             const float* __restrict__ emb_W,
                             const float* __restrict__ emb_b,
                             const float* __restrict__ cls_tok,
                             float* __restrict__ x) {
    int row = blockIdx.x;          // b*T + t
    int b = row / T, t = row % T;
    int tid = threadIdx.x;         // 256
    __shared__ float sv[F];
    if (t > 0) {
        if (tid < F) sv[tid] = src[(b * S + (t - 1)) * F + tid];
    }
    __syncthreads();
    const float LOG1E4 = 9.210340371976184f;   // ln(10000)
    #pragma unroll
    for (int l = 0; l < 2; ++l) {
        int d = tid + l * 256;
        float je = (float)(d & ~1);
        float ang = (float)t * expf(-(je / (float)D) * LOG1E4);
        float pe = (d & 1) ? cosf(ang) : sinf(ang);
        float val;
        if (t == 0) {
            val = cls_tok[d];
        } else {
            float acc = emb_b[d];
            #pragma unroll 8
            for (int f = 0; f < F; ++f) acc += sv[f] * emb_W[f * D + d];
            val = acc;
        }
        x[row * D + d] = val + pe;
    }
}

// ---------------- layernorm: out = (x-m)*rstd*g + b ----------------
__global__ void ln_kernel(const float* __restrict__ xin,
                          const float* __restrict__ g,
                          const float* __restrict__ bb,
                          float* __restrict__ out) {
    int row = blockIdx.x;
    int tid = threadIdx.x;  // 256
    float v0 = xin[row * D + tid];
    float v1 = xin[row * D + tid + 256];
    float s = v0 + v1;
    __shared__ float red[4];
    __shared__ float red2[4];
    #pragma unroll
    for (int off = 32; off > 0; off >>= 1) s += __shfl_down(s, off, 64);
    if ((tid & 63) == 0) red[tid >> 6] = s;
    __syncthreads();
    if (tid == 0) red[0] = (red[0] + red[1] + red[2] + red[3]) * (1.0f / (float)D);
    __syncthreads();
    float mean = red[0];
    float d0 = v0 - mean, d1 = v1 - mean;
    float sq = d0 * d0 + d1 * d1;
    #pragma unroll
    for (int off = 32; off > 0; off >>= 1) sq += __shfl_down(sq, off, 64);
    if ((tid & 63) == 0) red2[tid >> 6] = sq;
    __syncthreads();
    if (tid == 0) red2[0] = rsqrtf((red2[0] + red2[1] + red2[2] + red2[3]) * (1.0f / (float)D) + EPS);
    __syncthreads();
    float rstd = red2[0];
    out[row * D + tid]       = d0 * rstd * g[tid] + bb[tid];
    out[row * D + tid + 256] = d1 * rstd * g[tid + 256] + bb[tid + 256];
}

// ---------------- qkv: per-token, all heads ----------------
__global__ void qkv_kernel(const float* __restrict__ h,
                           const float* __restrict__ Wq, const float* __restrict__ bq,
                           const float* __restrict__ Wk, const float* __restrict__ bk,
                           const float* __restrict__ Wv, const float* __restrict__ bv,
                           float* __restrict__ q, float* __restrict__ k, float* __restrict__ v) {
    int row = blockIdx.x;            // b*T + t
    int b = row / T, t = row % T;
    int tid = threadIdx.x;           // 512
    int hh = tid >> 6;
    int e = tid & 63;
    __shared__ float hv[D];
    hv[tid] = h[row * D + tid];
    __syncthreads();
    const float* hrow = &hv[hh * DH];
    float aq = bq[hh * DH + e], ak = bk[hh * DH + e], av = bv[hh * DH + e];
    #pragma unroll 8
    for (int d = 0; d < DH; ++d) {
        float xv = hrow[d];
        aq += xv * Wq[(hh * DH + d) * DH + e];
        ak += xv * Wk[(hh * DH + d) * DH + e];
        av += xv * Wv[(hh * DH + d) * DH + e];
    }
    int o = ((b * H + hh) * T + t) * DH + e;
    q[o] = aq; k[o] = ak; v[o] = av;
}

// ---------------- attention (fused softmax, residual add into x) ----------------
__global__ void attn_kernel(const float* __restrict__ q,
                            const float* __restrict__ k,
                            const float* __restrict__ v,
                            float* __restrict__ x) {
    int tq = blockIdx.x;       // 0..T-1
    int bh = blockIdx.y;       // b*H + h
    int b = bh / H, hh = bh % H;
    int tid = threadIdx.x;     // 256
    __shared__ float qv[DH];
    __shared__ float p[T];
    __shared__ float red[4];
    __shared__ float part[4][DH];
    if (tid < DH) qv[tid] = q[((size_t)bh * T + tq) * DH + tid];
    __syncthreads();
    float sc[2];
    float smax = -1e30f;
    #pragma unroll
    for (int l = 0; l < 2; ++l) {
        int tk = tid + l * 256;
        const float* krow = &k[((size_t)bh * T + tk) * DH];
        float acc = 0.f;
        #pragma unroll 16
        for (int d = 0; d < DH; ++d) acc += qv[d] * krow[d];
        acc *= 0.125f;  // 1/sqrt(64)
        sc[l] = acc;
        smax = fmaxf(smax, acc);
    }
    #pragma unroll
    for (int off = 32; off > 0; off >>= 1) smax = fmaxf(smax, __shfl_down(smax, off, 64));
    if ((tid & 63) == 0) red[tid >> 6] = smax;
    __syncthreads();
    if (tid == 0) red[0] = fmaxf(fmaxf(red[0], red[1]), fmaxf(red[2], red[3]));
    __syncthreads();
    float m = red[0];
    __syncthreads();
    float esum = 0.f;
    #pragma unroll
    for (int l = 0; l < 2; ++l) {
        float e = __expf(sc[l] - m);
        esum += e;
        p[tid + l * 256] = e;
    }
    #pragma unroll
    for (int off = 32; off > 0; off >>= 1) esum += __shfl_down(esum, off, 64);
    if ((tid & 63) == 0) red[tid >> 6] = esum;
    __syncthreads();
    if (tid == 0) red[0] = red[0] + red[1] + red[2] + red[3];
    __syncthreads();
    float rinv = 1.0f / red[0];
    // PV
    int e = tid & 63, g = tid >> 6;
    float acc = 0.f;
    const float* vbase = &v[(size_t)bh * T * DH];
    for (int tk = g * 128; tk < g * 128 + 128; ++tk)
        acc += p[tk] * vbase[tk * DH + e];
    part[g][e] = acc;
    __syncthreads();
    if (tid < DH) {
        float o = (part[0][tid] + part[1][tid] + part[2][tid] + part[3][tid]) * rinv;
        x[((size_t)(b * T + tq)) * D + hh * DH + tid] += o;
    }
}

// ---------------- GEMM: MODE 0: C = gelu(A@W + bias); MODE 1: C += A@W + bias ----------------
template<int MODE>
__global__ void gemm_kernel(const float* __restrict__ A, int K,
                            const float* __restrict__ Wm, int N,
                            const float* __restrict__ bias,
                            float* __restrict__ C) {
    __shared__ float As[16][65];
    __shared__ float Bs[16][65];
    int tid = threadIdx.x;         // 256
    int m0 = blockIdx.x * 64;
    int n0 = blockIdx.y * 64;
    int tx = tid & 15, ty = tid >> 4;
    float acc[4][4] = {};
    for (int k0 = 0; k0 < K; k0 += 16) {
        #pragma unroll
        for (int l = 0; l < 4; ++l) {
            int e = tid + l * 256;
            int kk = e & 15, mm = e >> 4;
            As[kk][mm] = A[(size_t)(m0 + mm) * K + k0 + kk];
        }
        #pragma unroll
        for (int l = 0; l < 4; ++l) {
            int e = tid + l * 256;
            int kk = e >> 6, nn = e & 63;
            Bs[kk][nn] = Wm[(size_t)(k0 + kk) * N + n0 + nn];
        }
        __syncthreads();
        #pragma unroll
        for (int kk = 0; kk < 16; ++kk) {
            float a[4], bv4[4];
            #pragma unroll
            for (int i = 0; i < 4; ++i) a[i] = As[kk][ty * 4 + i];
            #pragma unroll
            for (int j = 0; j < 4; ++j) bv4[j] = Bs[kk][tx * 4 + j];
            #pragma unroll
            for (int i = 0; i < 4; ++i)
                #pragma unroll
                for (int j = 0; j < 4; ++j) acc[i][j] += a[i] * bv4[j];
        }
        __syncthreads();
    }
    #pragma unroll
    for (int i = 0; i < 4; ++i) {
        int m = m0 + ty * 4 + i;
        #pragma unroll
        for (int j = 0; j < 4; ++j) {
            int n = n0 + tx * 4 + j;
            float val = acc[i][j] + bias[n];
            if (MODE == 0) {
                val = 0.5f * val * (1.0f + erff(val * 0.70710678118f));
                C[(size_t)m * N + n] = val;
            } else {
                C[(size_t)m * N + n] += val;
            }
        }
    }
}

// ---------------- head: out[b] = sigmoid(x[b,0,:] . head_W + head_b) ----------------
__global__ void head_kernel(const float* __restrict__ x,
                            const float* __restrict__ hw,
                            const float* __restrict__ hb,
                            float* __restrict__ out) {
    int b = blockIdx.x;
    int tid = threadIdx.x; // 512
    float s = x[(size_t)b * T * D + tid] * hw[tid];
    #pragma unroll
    for (int off = 32; off > 0; off >>= 1) s += __shfl_down(s, off, 64);
    __shared__ float red[8];
    if ((tid & 63) == 0) red[tid >> 6] = s;
    __syncthreads();
    if (tid == 0) {
        float t = 0.f;
        #pragma unroll
        for (int i = 0; i < 8; ++i) t += red[i];
        out[b] = 1.0f / (1.0f + __expf(-(t + hb[0])));
    }
}

extern "C" void kernel_launch(void* const* d_in, const int* in_sizes, int n_in,
                              void* d_out, int out_size, void* d_ws, size_t ws_size,
                              hipStream_t stream) {
    const float* src     = (const float*)d_in[0];
    const float* emb_W   = (const float*)d_in[1];
    const float* emb_b   = (const float*)d_in[2];
    const float* cls_tok = (const float*)d_in[3];
    const float* ln1_g   = (const float*)d_in[4];
    const float* ln1_b   = (const float*)d_in[5];
    const float* Wq      = (const float*)d_in[6];
    const float* bq      = (const float*)d_in[7];
    const float* Wk      = (const float*)d_in[8];
    const float* bk      = (const float*)d_in[9];
    const float* Wv      = (const float*)d_in[10];
    const float* bv      = (const float*)d_in[11];
    const float* ln2_g   = (const float*)d_in[12];
    const float* ln2_b   = (const float*)d_in[13];
    const float* W1      = (const float*)d_in[14];
    const float* b1      = (const float*)d_in[15];
    const float* W2      = (const float*)d_in[16];
    const float* b2      = (const float*)d_in[17];
    const float* head_W  = (const float*)d_in[18];
    const float* head_b  = (const float*)d_in[19];

    float* ws = (float*)d_ws;
    const size_t NTOK = (size_t)B * T;         // 8192
    float* x = ws;                              // B*T*D
    float* h = x + NTOK * D;                    // B*T*D
    float* q = h + NTOK * D;                    // B*H*T*DH (= B*T*D)
    float* k = q + NTOK * D;
    float* v = k + NTOK * D;
    float* u = v + NTOK * D;                    // B*T*MLPD

    embed_kernel<<<B * T, 256, 0, stream>>>(src, emb_W, emb_b, cls_tok, x);

    for (int i = 0; i < NB; ++i) {
        ln_kernel<<<B * T, 256, 0, stream>>>(x, ln1_g + i * D, ln1_b + i * D, h);
        qkv_kernel<<<B * T, 512, 0, stream>>>(h,
            Wq + (size_t)i * H * DH * DH, bq + (size_t)i * H * DH,
            Wk + (size_t)i * H * DH * DH, bk + (size_t)i * H * DH,
            Wv + (size_t)i * H * DH * DH, bv + (size_t)i * H * DH,
            q, k, v);
        attn_kernel<<<dim3(T, B * H), 256, 0, stream>>>(q, k, v, x);
        ln_kernel<<<B * T, 256, 0, stream>>>(x, ln2_g + i * D, ln2_b + i * D, h);
        gemm_kernel<0><<<dim3(B * T / 64, MLPD / 64), 256, 0, stream>>>(
            h, D, W1 + (size_t)i * D * MLPD, MLPD, b1 + (size_t)i * MLPD, u);
        gemm_kernel<1><<<dim3(B * T / 64, D / 64), 256, 0, stream>>>(
            u, MLPD, W2 + (size_t)i * MLPD * D, D, b2 + (size_t)i * D, x);
    }

    head_kernel<<<B, 512, 0, stream>>>(x, head_W, head_b, (float*)d_out);
}

// Round 2
// 7096.532 us; speedup vs baseline: 1.6901x; 1.6901x over previous
//
#include <hip/hip_runtime.h>
#include <math.h>

#define B 16
#define S 511
#define F 128
#define D 512
#define H 8
#define NB 6
#define DH 64
#define MLPD 2048
#define T 512
#define EPS 1e-5f

// ---------------- embed: x = concat(cls, src@emb_W+emb_b) + pos ----------------
__global__ void embed_kernel(const float* __restrict__ src,
                             const float* __restrict__ emb_W,
                             const float* __restrict__ emb_b,
                             const float* __restrict__ cls_tok,
                             float* __restrict__ x) {
    int row = blockIdx.x;          // b*T + t
    int b = row / T, t = row % T;
    int tid = threadIdx.x;         // 256
    __shared__ float sv[F];
    if (t > 0) {
        if (tid < F) sv[tid] = src[(b * S + (t - 1)) * F + tid];
    }
    __syncthreads();
    const float LOG1E4 = 9.210340371976184f;   // ln(10000)
    #pragma unroll
    for (int l = 0; l < 2; ++l) {
        int d = tid + l * 256;
        float je = (float)(d & ~1);
        float ang = (float)t * expf(-(je / (float)D) * LOG1E4);
        float pe = (d & 1) ? cosf(ang) : sinf(ang);
        float val;
        if (t == 0) {
            val = cls_tok[d];
        } else {
            float acc = emb_b[d];
            #pragma unroll 8
            for (int f = 0; f < F; ++f) acc += sv[f] * emb_W[f * D + d];
            val = acc;
        }
        x[row * D + d] = val + pe;
    }
}

// ---------------- layernorm: out = (x-m)*rstd*g + b ----------------
__global__ void ln_kernel(const float* __restrict__ xin,
                          const float* __restrict__ g,
                          const float* __restrict__ bb,
                          float* __restrict__ out) {
    int row = blockIdx.x;
    int tid = threadIdx.x;  // 256
    float v0 = xin[row * D + tid];
    float v1 = xin[row * D + tid + 256];
    float s = v0 + v1;
    __shared__ float red[4];
    __shared__ float red2[4];
    #pragma unroll
    for (int off = 32; off > 0; off >>= 1) s += __shfl_down(s, off, 64);
    if ((tid & 63) == 0) red[tid >> 6] = s;
    __syncthreads();
    if (tid == 0) red[0] = (red[0] + red[1] + red[2] + red[3]) * (1.0f / (float)D);
    __syncthreads();
    float mean = red[0];
    float d0 = v0 - mean, d1 = v1 - mean;
    float sq = d0 * d0 + d1 * d1;
    #pragma unroll
    for (int off = 32; off > 0; off >>= 1) sq += __shfl_down(sq, off, 64);
    if ((tid & 63) == 0) red2[tid >> 6] = sq;
    __syncthreads();
    if (tid == 0) red2[0] = rsqrtf((red2[0] + red2[1] + red2[2] + red2[3]) * (1.0f / (float)D) + EPS);
    __syncthreads();
    float rstd = red2[0];
    out[row * D + tid]       = d0 * rstd * g[tid] + bb[tid];
    out[row * D + tid + 256] = d1 * rstd * g[tid + 256] + bb[tid + 256];
}

// ---------------- qkv: per-token, all heads ----------------
__global__ void qkv_kernel(const float* __restrict__ h,
                           const float* __restrict__ Wq, const float* __restrict__ bq,
                           const float* __restrict__ Wk, const float* __restrict__ bk,
                           const float* __restrict__ Wv, const float* __restrict__ bv,
                           float* __restrict__ q, float* __restrict__ k, float* __restrict__ v) {
    int row = blockIdx.x;            // b*T + t
    int b = row / T, t = row % T;
    int tid = threadIdx.x;           // 512
    int hh = tid >> 6;
    int e = tid & 63;
    __shared__ float hv[D];
    hv[tid] = h[row * D + tid];
    __syncthreads();
    const float* hrow = &hv[hh * DH];
    float aq = bq[hh * DH + e], ak = bk[hh * DH + e], av = bv[hh * DH + e];
    #pragma unroll 8
    for (int d = 0; d < DH; ++d) {
        float xv = hrow[d];
        aq += xv * Wq[(hh * DH + d) * DH + e];
        ak += xv * Wk[(hh * DH + d) * DH + e];
        av += xv * Wv[(hh * DH + d) * DH + e];
    }
    int o = ((b * H + hh) * T + t) * DH + e;
    q[o] = aq; k[o] = ak; v[o] = av;
}

// ---------------- flash-style attention ----------------
// grid: (T/64, B*H); block: 256 threads.
// Each block: 64 queries x full K/V (8 tiles of 64 keys), online softmax.
// Thread (r = tid>>2, j = tid&3): query row r, key-slice / dim-slice j*16..j*16+15.
#define APAD 68   // 64 + 4 pad: keeps 16B alignment, stride%32 = 4 -> max 2-way bank alias (free)
__global__ __launch_bounds__(256) void attn_kernel(const float* __restrict__ q,
                                                   const float* __restrict__ k,
                                                   const float* __restrict__ v,
                                                   float* __restrict__ x) {
    int qt = blockIdx.x;       // 0..7 query tile
    int bh = blockIdx.y;       // b*H + h
    int b = bh >> 3, hh = bh & 7;
    int tid = threadIdx.x;     // 256
    int r = tid >> 2;          // 0..63
    int j = tid & 3;           // 0..3

    __shared__ float Qs[64][APAD];   // reused as Ps after Q copied to regs
    __shared__ float Ks[64][APAD];
    __shared__ float Vs[64][APAD];
    float (*Ps)[APAD] = Qs;

    // ---- load Q tile (64x64 floats), then copy my row to registers ----
    const float* qbase = q + ((size_t)bh * T + (size_t)qt * 64) * DH;
    #pragma unroll
    for (int l = 0; l < 4; ++l) {
        int idx = tid + l * 256;          // 0..1023 float4s
        int row = idx >> 4, c4 = idx & 15;
        float4 t4 = *(const float4*)(qbase + row * DH + c4 * 4);
        *(float4*)&Qs[row][c4 * 4] = t4;
    }
    __syncthreads();
    float4 Qreg[16];
    #pragma unroll
    for (int d4 = 0; d4 < 16; ++d4) Qreg[d4] = *(float4*)&Qs[r][d4 * 4];
    // NOTE: barrier before first Ps write is the sync inside the first loop iter.

    float m_i = -1e30f, l_i = 0.f;
    float4 O4[4] = {};

    const float* kbase = k + (size_t)bh * T * DH;
    const float* vbase = v + (size_t)bh * T * DH;

    for (int kt = 0; kt < T / 64; ++kt) {
        // ---- stage K,V tiles ----
        #pragma unroll
        for (int l = 0; l < 4; ++l) {
            int idx = tid + l * 256;
            int row = idx >> 4, c4 = idx & 15;
            float4 kv4 = *(const float4*)(kbase + (size_t)(kt * 64 + row) * DH + c4 * 4);
            *(float4*)&Ks[row][c4 * 4] = kv4;
            float4 vv4 = *(const float4*)(vbase + (size_t)(kt * 64 + row) * DH + c4 * 4);
            *(float4*)&Vs[row][c4 * 4] = vv4;
        }
        __syncthreads();   // [A] K/V visible; also guards Qreg-read (kt=0) / prev PV (kt>0... see [C])

        // ---- scores for my 16 keys ----
        float s[16];
        float tmax = -1e30f;
        #pragma unroll
        for (int kk = 0; kk < 16; ++kk) {
            const float* krow = &Ks[j * 16 + kk][0];
            float4 acc = {0.f, 0.f, 0.f, 0.f};
            #pragma unroll
            for (int d4 = 0; d4 < 16; ++d4) {
                float4 k4 = *(const float4*)&krow[d4 * 4];
                acc.x += Qreg[d4].x * k4.x;
                acc.y += Qreg[d4].y * k4.y;
                acc.z += Qreg[d4].z * k4.z;
                acc.w += Qreg[d4].w * k4.w;
            }
            s[kk] = (acc.x + acc.y + acc.z + acc.w) * 0.125f;
            tmax = fmaxf(tmax, s[kk]);
        }
        // row max across the 4 slice-lanes (adjacent lanes, same wave)
        tmax = fmaxf(tmax, __shfl_xor(tmax, 1));
        tmax = fmaxf(tmax, __shfl_xor(tmax, 2));
        float m_new = fmaxf(m_i, tmax);
        float alpha = __expf(m_i - m_new);
        float psum = 0.f;
        #pragma unroll
        for (int kk = 0; kk < 16; ++kk) {
            float p = __expf(s[kk] - m_new);
            Ps[r][j * 16 + kk] = p;
            psum += p;
        }
        psum += __shfl_xor(psum, 1);
        psum += __shfl_xor(psum, 2);
        l_i = l_i * alpha + psum;
        m_i = m_new;
        #pragma unroll
        for (int c = 0; c < 4; ++c) {
            O4[c].x *= alpha; O4[c].y *= alpha; O4[c].z *= alpha; O4[c].w *= alpha;
        }
        __syncthreads();   // [B] Ps visible to all

        // ---- PV: O[j*16..+15] += sum_kk2 P[r][kk2] * V[kk2][dims] ----
        #pragma unroll 8
        for (int kk2 = 0; kk2 < 64; ++kk2) {
            float p = Ps[r][kk2];
            #pragma unroll
            for (int c = 0; c < 4; ++c) {
                float4 vv = *(const float4*)&Vs[kk2][j * 16 + c * 4];
                O4[c].x += p * vv.x;
                O4[c].y += p * vv.y;
                O4[c].z += p * vv.z;
                O4[c].w += p * vv.w;
            }
        }
        __syncthreads();   // [C] PV done before next iter overwrites Ks/Vs/Ps
    }

    // ---- epilogue: residual add into x ----
    float rl = 1.0f / l_i;
    float* xp = x + ((size_t)(b * T) + (size_t)qt * 64 + r) * D + hh * DH + j * 16;
    #pragma unroll
    for (int c = 0; c < 4; ++c) {
        float4 xv = *(float4*)&xp[c * 4];
        xv.x += O4[c].x * rl;
        xv.y += O4[c].y * rl;
        xv.z += O4[c].z * rl;
        xv.w += O4[c].w * rl;
        *(float4*)&xp[c * 4] = xv;
    }
}

// ---------------- GEMM: MODE 0: C = gelu(A@W + bias); MODE 1: C += A@W + bias ----------------
template<int MODE>
__global__ void gemm_kernel(const float* __restrict__ A, int K,
                            const float* __restrict__ Wm, int N,
                            const float* __restrict__ bias,
                            float* __restrict__ C) {
    __shared__ float As[16][65];
    __shared__ float Bs[16][65];
    int tid = threadIdx.x;         // 256
    int m0 = blockIdx.x * 64;
    int n0 = blockIdx.y * 64;
    int tx = tid & 15, ty = tid >> 4;
    float acc[4][4] = {};
    for (int k0 = 0; k0 < K; k0 += 16) {
        #pragma unroll
        for (int l = 0; l < 4; ++l) {
            int e = tid + l * 256;
            int kk = e & 15, mm = e >> 4;
            As[kk][mm] = A[(size_t)(m0 + mm) * K + k0 + kk];
        }
        #pragma unroll
        for (int l = 0; l < 4; ++l) {
            int e = tid + l * 256;
            int kk = e >> 6, nn = e & 63;
            Bs[kk][nn] = Wm[(size_t)(k0 + kk) * N + n0 + nn];
        }
        __syncthreads();
        #pragma unroll
        for (int kk = 0; kk < 16; ++kk) {
            float a[4], bv4[4];
            #pragma unroll
            for (int i = 0; i < 4; ++i) a[i] = As[kk][ty * 4 + i];
            #pragma unroll
            for (int j = 0; j < 4; ++j) bv4[j] = Bs[kk][tx * 4 + j];
            #pragma unroll
            for (int i = 0; i < 4; ++i)
                #pragma unroll
                for (int j = 0; j < 4; ++j) acc[i][j] += a[i] * bv4[j];
        }
        __syncthreads();
    }
    #pragma unroll
    for (int i = 0; i < 4; ++i) {
        int m = m0 + ty * 4 + i;
        #pragma unroll
        for (int j = 0; j < 4; ++j) {
            int n = n0 + tx * 4 + j;
            float val = acc[i][j] + bias[n];
            if (MODE == 0) {
                val = 0.5f * val * (1.0f + erff(val * 0.70710678118f));
                C[(size_t)m * N + n] = val;
            } else {
                C[(size_t)m * N + n] += val;
            }
        }
    }
}

// ---------------- head: out[b] = sigmoid(x[b,0,:] . head_W + head_b) ----------------
__global__ void head_kernel(const float* __restrict__ x,
                            const float* __restrict__ hw,
                            const float* __restrict__ hb,
                            float* __restrict__ out) {
    int b = blockIdx.x;
    int tid = threadIdx.x; // 512
    float s = x[(size_t)b * T * D + tid] * hw[tid];
    #pragma unroll
    for (int off = 32; off > 0; off >>= 1) s += __shfl_down(s, off, 64);
    __shared__ float red[8];
    if ((tid & 63) == 0) red[tid >> 6] = s;
    __syncthreads();
    if (tid == 0) {
        float t = 0.f;
        #pragma unroll
        for (int i = 0; i < 8; ++i) t += red[i];
        out[b] = 1.0f / (1.0f + __expf(-(t + hb[0])));
    }
}

extern "C" void kernel_launch(void* const* d_in, const int* in_sizes, int n_in,
                              void* d_out, int out_size, void* d_ws, size_t ws_size,
                              hipStream_t stream) {
    const float* src     = (const float*)d_in[0];
    const float* emb_W   = (const float*)d_in[1];
    const float* emb_b   = (const float*)d_in[2];
    const float* cls_tok = (const float*)d_in[3];
    const float* ln1_g   = (const float*)d_in[4];
    const float* ln1_b   = (const float*)d_in[5];
    const float* Wq      = (const float*)d_in[6];
    const float* bq      = (const float*)d_in[7];
    const float* Wk      = (const float*)d_in[8];
    const float* bk      = (const float*)d_in[9];
    const float* Wv      = (const float*)d_in[10];
    const float* bv      = (const float*)d_in[11];
    const float* ln2_g   = (const float*)d_in[12];
    const float* ln2_b   = (const float*)d_in[13];
    const float* W1      = (const float*)d_in[14];
    const float* b1      = (const float*)d_in[15];
    const float* W2      = (const float*)d_in[16];
    const float* b2      = (const float*)d_in[17];
    const float* head_W  = (const float*)d_in[18];
    const float* head_b  = (const float*)d_in[19];

    float* ws = (float*)d_ws;
    const size_t NTOK = (size_t)B * T;         // 8192
    float* x = ws;                              // B*T*D
    float* h = x + NTOK * D;                    // B*T*D
    float* q = h + NTOK * D;                    // B*H*T*DH (= B*T*D)
    float* k = q + NTOK * D;
    float* v = k + NTOK * D;
    float* u = v + NTOK * D;                    // B*T*MLPD

    embed_kernel<<<B * T, 256, 0, stream>>>(src, emb_W, emb_b, cls_tok, x);

    for (int i = 0; i < NB; ++i) {
        ln_kernel<<<B * T, 256, 0, stream>>>(x, ln1_g + i * D, ln1_b + i * D, h);
        qkv_kernel<<<B * T, 512, 0, stream>>>(h,
            Wq + (size_t)i * H * DH * DH, bq + (size_t)i * H * DH,
            Wk + (size_t)i * H * DH * DH, bk + (size_t)i * H * DH,
            Wv + (size_t)i * H * DH * DH, bv + (size_t)i * H * DH,
            q, k, v);
        attn_kernel<<<dim3(T / 64, B * H), 256, 0, stream>>>(q, k, v, x);
        ln_kernel<<<B * T, 256, 0, stream>>>(x, ln2_g + i * D, ln2_b + i * D, h);
        gemm_kernel<0><<<dim3(B * T / 64, MLPD / 64), 256, 0, stream>>>(
            h, D, W1 + (size_t)i * D * MLPD, MLPD, b1 + (size_t)i * MLPD, u);
        gemm_kernel<1><<<dim3(B * T / 64, D / 64), 256, 0, stream>>>(
            u, MLPD, W2 + (size_t)i * MLPD * D, D, b2 + (size_t)i * D, x);
    }

    head_kernel<<<B, 512, 0, stream>>>(x, head_W, head_b, (float*)d_out);
}

// Round 3
// 3609.659 us; speedup vs baseline: 3.3228x; 1.9660x over previous
//
#include <hip/hip_runtime.h>
#include <hip/hip_bf16.h>
#include <math.h>

#define B 16
#define S 511
#define F 128
#define D 512
#define H 8
#define NB 6
#define DH 64
#define MLPD 2048
#define T 512
#define EPS 1e-5f

typedef unsigned short ushort;
typedef __attribute__((ext_vector_type(8))) short short8;
typedef __attribute__((ext_vector_type(4))) float floatx4;

// ---------------- embed ----------------
__global__ void embed_kernel(const float* __restrict__ src,
                             const float* __restrict__ emb_W,
                             const float* __restrict__ emb_b,
                             const float* __restrict__ cls_tok,
                             float* __restrict__ x) {
    int row = blockIdx.x;          // b*T + t
    int b = row / T, t = row % T;
    int tid = threadIdx.x;         // 256
    __shared__ float sv[F];
    if (t > 0) {
        if (tid < F) sv[tid] = src[(b * S + (t - 1)) * F + tid];
    }
    __syncthreads();
    const float LOG1E4 = 9.210340371976184f;
    #pragma unroll
    for (int l = 0; l < 2; ++l) {
        int d = tid + l * 256;
        float je = (float)(d & ~1);
        float ang = (float)t * expf(-(je / (float)D) * LOG1E4);
        float pe = (d & 1) ? cosf(ang) : sinf(ang);
        float val;
        if (t == 0) {
            val = cls_tok[d];
        } else {
            float acc = emb_b[d];
            #pragma unroll 8
            for (int f = 0; f < F; ++f) acc += sv[f] * emb_W[f * D + d];
            val = acc;
        }
        x[row * D + d] = val + pe;
    }
}

// ---------------- layernorm (templated output: fp32 for QKV path, bf16 for MLP path) ----------------
template<typename OUT_T>
__global__ void ln_kernel(const float* __restrict__ xin,
                          const float* __restrict__ g,
                          const float* __restrict__ bb,
                          OUT_T* __restrict__ out) {
    int row = blockIdx.x;
    int tid = threadIdx.x;  // 256
    float v0 = xin[row * D + tid];
    float v1 = xin[row * D + tid + 256];
    float s = v0 + v1;
    __shared__ float red[4];
    __shared__ float red2[4];
    #pragma unroll
    for (int off = 32; off > 0; off >>= 1) s += __shfl_down(s, off, 64);
    if ((tid & 63) == 0) red[tid >> 6] = s;
    __syncthreads();
    if (tid == 0) red[0] = (red[0] + red[1] + red[2] + red[3]) * (1.0f / (float)D);
    __syncthreads();
    float mean = red[0];
    float d0 = v0 - mean, d1 = v1 - mean;
    float sq = d0 * d0 + d1 * d1;
    #pragma unroll
    for (int off = 32; off > 0; off >>= 1) sq += __shfl_down(sq, off, 64);
    if ((tid & 63) == 0) red2[tid >> 6] = sq;
    __syncthreads();
    if (tid == 0) red2[0] = rsqrtf((red2[0] + red2[1] + red2[2] + red2[3]) * (1.0f / (float)D) + EPS);
    __syncthreads();
    float rstd = red2[0];
    float o0 = d0 * rstd * g[tid] + bb[tid];
    float o1 = d1 * rstd * g[tid + 256] + bb[tid + 256];
    out[row * D + tid]       = (OUT_T)o0;
    out[row * D + tid + 256] = (OUT_T)o1;
}

// ---------------- qkv: per-token, all heads ----------------
__global__ void qkv_kernel(const float* __restrict__ h,
                           const float* __restrict__ Wq, const float* __restrict__ bq,
                           const float* __restrict__ Wk, const float* __restrict__ bk,
                           const float* __restrict__ Wv, const float* __restrict__ bv,
                           float* __restrict__ q, float* __restrict__ k, float* __restrict__ v) {
    int row = blockIdx.x;            // b*T + t
    int b = row / T, t = row % T;
    int tid = threadIdx.x;           // 512
    int hh = tid >> 6;
    int e = tid & 63;
    __shared__ float hv[D];
    hv[tid] = h[row * D + tid];
    __syncthreads();
    const float* hrow = &hv[hh * DH];
    float aq = bq[hh * DH + e], ak = bk[hh * DH + e], av = bv[hh * DH + e];
    #pragma unroll 8
    for (int d = 0; d < DH; ++d) {
        float xv = hrow[d];
        aq += xv * Wq[(hh * DH + d) * DH + e];
        ak += xv * Wk[(hh * DH + d) * DH + e];
        av += xv * Wv[(hh * DH + d) * DH + e];
    }
    int o = ((b * H + hh) * T + t) * DH + e;
    q[o] = aq; k[o] = ak; v[o] = av;
}

// ---------------- flash-style attention (unchanged from round 2) ----------------
#define APAD 68
__global__ __launch_bounds__(256) void attn_kernel(const float* __restrict__ q,
                                                   const float* __restrict__ k,
                                                   const float* __restrict__ v,
                                                   float* __restrict__ x) {
    int qt = blockIdx.x;
    int bh = blockIdx.y;
    int b = bh >> 3, hh = bh & 7;
    int tid = threadIdx.x;
    int r = tid >> 2;
    int j = tid & 3;

    __shared__ float Qs[64][APAD];
    __shared__ float Ks[64][APAD];
    __shared__ float Vs[64][APAD];
    float (*Ps)[APAD] = Qs;

    const float* qbase = q + ((size_t)bh * T + (size_t)qt * 64) * DH;
    #pragma unroll
    for (int l = 0; l < 4; ++l) {
        int idx = tid + l * 256;
        int row = idx >> 4, c4 = idx & 15;
        float4 t4 = *(const float4*)(qbase + row * DH + c4 * 4);
        *(float4*)&Qs[row][c4 * 4] = t4;
    }
    __syncthreads();
    float4 Qreg[16];
    #pragma unroll
    for (int d4 = 0; d4 < 16; ++d4) Qreg[d4] = *(float4*)&Qs[r][d4 * 4];

    float m_i = -1e30f, l_i = 0.f;
    float4 O4[4] = {};

    const float* kbase = k + (size_t)bh * T * DH;
    const float* vbase = v + (size_t)bh * T * DH;

    for (int kt = 0; kt < T / 64; ++kt) {
        #pragma unroll
        for (int l = 0; l < 4; ++l) {
            int idx = tid + l * 256;
            int row = idx >> 4, c4 = idx & 15;
            float4 kv4 = *(const float4*)(kbase + (size_t)(kt * 64 + row) * DH + c4 * 4);
            *(float4*)&Ks[row][c4 * 4] = kv4;
            float4 vv4 = *(const float4*)(vbase + (size_t)(kt * 64 + row) * DH + c4 * 4);
            *(float4*)&Vs[row][c4 * 4] = vv4;
        }
        __syncthreads();

        float s[16];
        float tmax = -1e30f;
        #pragma unroll
        for (int kk = 0; kk < 16; ++kk) {
            const float* krow = &Ks[j * 16 + kk][0];
            float4 acc = {0.f, 0.f, 0.f, 0.f};
            #pragma unroll
            for (int d4 = 0; d4 < 16; ++d4) {
                float4 k4 = *(const float4*)&krow[d4 * 4];
                acc.x += Qreg[d4].x * k4.x;
                acc.y += Qreg[d4].y * k4.y;
                acc.z += Qreg[d4].z * k4.z;
                acc.w += Qreg[d4].w * k4.w;
            }
            s[kk] = (acc.x + acc.y + acc.z + acc.w) * 0.125f;
            tmax = fmaxf(tmax, s[kk]);
        }
        tmax = fmaxf(tmax, __shfl_xor(tmax, 1));
        tmax = fmaxf(tmax, __shfl_xor(tmax, 2));
        float m_new = fmaxf(m_i, tmax);
        float alpha = __expf(m_i - m_new);
        float psum = 0.f;
        #pragma unroll
        for (int kk = 0; kk < 16; ++kk) {
            float p = __expf(s[kk] - m_new);
            Ps[r][j * 16 + kk] = p;
            psum += p;
        }
        psum += __shfl_xor(psum, 1);
        psum += __shfl_xor(psum, 2);
        l_i = l_i * alpha + psum;
        m_i = m_new;
        #pragma unroll
        for (int c = 0; c < 4; ++c) {
            O4[c].x *= alpha; O4[c].y *= alpha; O4[c].z *= alpha; O4[c].w *= alpha;
        }
        __syncthreads();

        #pragma unroll 8
        for (int kk2 = 0; kk2 < 64; ++kk2) {
            float p = Ps[r][kk2];
            #pragma unroll
            for (int c = 0; c < 4; ++c) {
                float4 vv = *(const float4*)&Vs[kk2][j * 16 + c * 4];
                O4[c].x += p * vv.x;
                O4[c].y += p * vv.y;
                O4[c].z += p * vv.z;
                O4[c].w += p * vv.w;
            }
        }
        __syncthreads();
    }

    float rl = 1.0f / l_i;
    float* xp = x + ((size_t)(b * T) + (size_t)qt * 64 + r) * D + hh * DH + j * 16;
    #pragma unroll
    for (int c = 0; c < 4; ++c) {
        float4 xv = *(float4*)&xp[c * 4];
        xv.x += O4[c].x * rl;
        xv.y += O4[c].y * rl;
        xv.z += O4[c].z * rl;
        xv.w += O4[c].w * rl;
        *(float4*)&xp[c * 4] = xv;
    }
}

// ---------------- weight transpose+cast: W [mat,K,N] fp32 -> Wt [mat,N,K] bf16 ----------------
__global__ void wtrans_kernel(const float* __restrict__ W,
                              __hip_bfloat16* __restrict__ Wt,
                              int K, int N) {
    int kb = blockIdx.x * 32, nb = blockIdx.y * 32, mat = blockIdx.z;
    __shared__ float tile[32][33];
    int tid = threadIdx.x; // 256
    int c = tid & 31, r0 = tid >> 5;
    const float* Wm = W + (size_t)mat * K * N;
    __hip_bfloat16* Wtm = Wt + (size_t)mat * K * N;
    #pragma unroll
    for (int l = 0; l < 4; ++l) {
        int r = r0 + l * 8;
        tile[r][c] = Wm[(size_t)(kb + r) * N + nb + c];
    }
    __syncthreads();
    #pragma unroll
    for (int l = 0; l < 4; ++l) {
        int r = r0 + l * 8;   // n-index within tile
        Wtm[(size_t)(nb + r) * K + kb + c] = __float2bfloat16(tile[c][r]);
    }
}

// ---------------- MFMA GEMM (m97 structure): C = A[M,K] @ Bt[N,K]^T ----------------
// MODE 0: C(bf16) = gelu(acc + bias)   MODE 1: C(fp32) += acc + bias
// block: 256 thr = 4 waves in 2x2; tile 128x128; BK=32; 16x16x32 bf16 MFMA, 4x4 acc/wave.
__device__ __forceinline__ void gload_lds16(const ushort* g, ushort* l) {
    __builtin_amdgcn_global_load_lds((const __attribute__((address_space(1))) unsigned int*)g,
                                     (__attribute__((address_space(3))) unsigned int*)l,
                                     16, 0, 0);
}

template<int MODE>
__global__ __launch_bounds__(256) void mfma_gemm(const ushort* __restrict__ A,
                                                 const ushort* __restrict__ Bt,
                                                 const float* __restrict__ bias,
                                                 void* __restrict__ Cv,
                                                 int M, int N, int K) {
    __shared__ ushort As[128 * 32];
    __shared__ ushort Bs[128 * 32];
    int tid = threadIdx.x;
    int lane = tid & 63;
    int w = __builtin_amdgcn_readfirstlane(tid >> 6);   // wave id, wave-uniform scalar
    int wr = (w >> 1) * 64, wc = (w & 1) * 64;
    int m0 = blockIdx.x * 128, n0 = blockIdx.y * 128;

    floatx4 acc[4][4];
    #pragma unroll
    for (int i = 0; i < 4; ++i)
        #pragma unroll
        for (int j = 0; j < 4; ++j) acc[i][j] = (floatx4)0.f;

    // staging: each wave fills 32 rows of As and 32 rows of Bs per K-step,
    // as 2 issues of 16 rows (64 lanes x 16B = 1024B = 16 rows x 64B).
    int lrow = lane >> 2;          // 0..15
    int lk = (lane & 3) * 8;       // element offset in k
    const ushort* Ag = A + (size_t)(m0 + 32 * w + lrow) * K + lk;
    const ushort* Bg = Bt + (size_t)(n0 + 32 * w + lrow) * K + lk;
    ushort* AsW = &As[(32 * w) * 32];
    ushort* BsW = &Bs[(32 * w) * 32];

    int fa = (lane & 15) * 32 + (lane >> 4) * 8;   // fragment read offset pattern

    for (int kt = 0; kt < K; kt += 32) {
        gload_lds16(Ag + kt, AsW);
        gload_lds16(Ag + kt + (size_t)16 * K, AsW + 16 * 32);
        gload_lds16(Bg + kt, BsW);
        gload_lds16(Bg + kt + (size_t)16 * K, BsW + 16 * 32);
        __syncthreads();   // staging visible (compiler emits vmcnt(0) before barrier)

        short8 af[4], bf[4];
        #pragma unroll
        for (int i = 0; i < 4; ++i) af[i] = *(const short8*)&As[(wr + 16 * i) * 32 + fa];
        #pragma unroll
        for (int j = 0; j < 4; ++j) bf[j] = *(const short8*)&Bs[(wc + 16 * j) * 32 + fa];
        #pragma unroll
        for (int i = 0; i < 4; ++i)
            #pragma unroll
            for (int j = 0; j < 4; ++j)
                acc[i][j] = __builtin_amdgcn_mfma_f32_16x16x32_bf16(af[i], bf[j], acc[i][j], 0, 0, 0);
        __syncthreads();   // reads done before next stage overwrites
    }

    // epilogue: C/D layout col=lane&15, row=(lane>>4)*4+reg  [m89/m91 verified]
    int rbase = (lane >> 4) * 4;
    int cidx = lane & 15;
    if (MODE == 0) {
        __hip_bfloat16* C = (__hip_bfloat16*)Cv;
        #pragma unroll
        for (int i = 0; i < 4; ++i) {
            #pragma unroll
            for (int j = 0; j < 4; ++j) {
                int gc = n0 + wc + 16 * j + cidx;
                float bv = bias[gc];
                int gr = m0 + wr + 16 * i + rbase;
                #pragma unroll
                for (int reg = 0; reg < 4; ++reg) {
                    float val = acc[i][j][reg] + bv;
                    val = 0.5f * val * (1.0f + erff(val * 0.70710678118f));
                    C[(size_t)(gr + reg) * N + gc] = __float2bfloat16(val);
                }
            }
        }
    } else {
        float* C = (float*)Cv;
        #pragma unroll
        for (int i = 0; i < 4; ++i) {
            #pragma unroll
            for (int j = 0; j < 4; ++j) {
                int gc = n0 + wc + 16 * j + cidx;
                float bv = bias[gc];
                int gr = m0 + wr + 16 * i + rbase;
                #pragma unroll
                for (int reg = 0; reg < 4; ++reg) {
                    C[(size_t)(gr + reg) * N + gc] += acc[i][j][reg] + bv;
                }
            }
        }
    }
}

// ---------------- head ----------------
__global__ void head_kernel(const float* __restrict__ x,
                            const float* __restrict__ hw,
                            const float* __restrict__ hb,
                            float* __restrict__ out) {
    int b = blockIdx.x;
    int tid = threadIdx.x; // 512
    float s = x[(size_t)b * T * D + tid] * hw[tid];
    #pragma unroll
    for (int off = 32; off > 0; off >>= 1) s += __shfl_down(s, off, 64);
    __shared__ float red[8];
    if ((tid & 63) == 0) red[tid >> 6] = s;
    __syncthreads();
    if (tid == 0) {
        float t = 0.f;
        #pragma unroll
        for (int i = 0; i < 8; ++i) t += red[i];
        out[b] = 1.0f / (1.0f + __expf(-(t + hb[0])));
    }
}

extern "C" void kernel_launch(void* const* d_in, const int* in_sizes, int n_in,
                              void* d_out, int out_size, void* d_ws, size_t ws_size,
                              hipStream_t stream) {
    const float* src     = (const float*)d_in[0];
    const float* emb_W   = (const float*)d_in[1];
    const float* emb_b   = (const float*)d_in[2];
    const float* cls_tok = (const float*)d_in[3];
    const float* ln1_g   = (const float*)d_in[4];
    const float* ln1_b   = (const float*)d_in[5];
    const float* Wq      = (const float*)d_in[6];
    const float* bq      = (const float*)d_in[7];
    const float* Wk      = (const float*)d_in[8];
    const float* bk      = (const float*)d_in[9];
    const float* Wv      = (const float*)d_in[10];
    const float* bv      = (const float*)d_in[11];
    const float* ln2_g   = (const float*)d_in[12];
    const float* ln2_b   = (const float*)d_in[13];
    const float* W1      = (const float*)d_in[14];
    const float* b1      = (const float*)d_in[15];
    const float* W2      = (const float*)d_in[16];
    const float* b2      = (const float*)d_in[17];
    const float* head_W  = (const float*)d_in[18];
    const float* head_b  = (const float*)d_in[19];

    const size_t NTOK = (size_t)B * T;          // 8192
    char* wsb = (char*)d_ws;
    float* x = (float*)wsb;                                    wsb += NTOK * D * 4;
    float* h = (float*)wsb;                                    wsb += NTOK * D * 4;  // fp32 ln1 out; aliased as bf16 ln2 out
    float* q = (float*)wsb;                                    wsb += NTOK * D * 4;
    float* k = (float*)wsb;                                    wsb += NTOK * D * 4;
    float* v = (float*)wsb;                                    wsb += NTOK * D * 4;
    __hip_bfloat16* u   = (__hip_bfloat16*)wsb;                wsb += NTOK * MLPD * 2;
    __hip_bfloat16* W1t = (__hip_bfloat16*)wsb;                wsb += (size_t)NB * D * MLPD * 2;
    __hip_bfloat16* W2t = (__hip_bfloat16*)wsb;                wsb += (size_t)NB * D * MLPD * 2;
    __hip_bfloat16* hb = (__hip_bfloat16*)h;   // alias: h dead after qkv, hb born at ln2

    // weight prep (every launch; ~25MB write)
    wtrans_kernel<<<dim3(D / 32, MLPD / 32, NB), 256, 0, stream>>>(W1, W1t, D, MLPD);
    wtrans_kernel<<<dim3(MLPD / 32, D / 32, NB), 256, 0, stream>>>(W2, W2t, MLPD, D);

    embed_kernel<<<B * T, 256, 0, stream>>>(src, emb_W, emb_b, cls_tok, x);

    for (int i = 0; i < NB; ++i) {
        ln_kernel<float><<<B * T, 256, 0, stream>>>(x, ln1_g + i * D, ln1_b + i * D, h);
        qkv_kernel<<<B * T, 512, 0, stream>>>(h,
            Wq + (size_t)i * H * DH * DH, bq + (size_t)i * H * DH,
            Wk + (size_t)i * H * DH * DH, bk + (size_t)i * H * DH,
            Wv + (size_t)i * H * DH * DH, bv + (size_t)i * H * DH,
            q, k, v);
        attn_kernel<<<dim3(T / 64, B * H), 256, 0, stream>>>(q, k, v, x);
        ln_kernel<__hip_bfloat16><<<B * T, 256, 0, stream>>>(x, ln2_g + i * D, ln2_b + i * D, hb);
        mfma_gemm<0><<<dim3(B * T / 128, MLPD / 128), 256, 0, stream>>>(
            (const ushort*)hb, (const ushort*)(W1t + (size_t)i * D * MLPD),
            b1 + (size_t)i * MLPD, u, B * T, MLPD, D);
        mfma_gemm<1><<<dim3(B * T / 128, D / 128), 256, 0, stream>>>(
            (const ushort*)u, (const ushort*)(W2t + (size_t)i * MLPD * D),
            b2 + (size_t)i * D, x, B * T, D, MLPD);
    }

    head_kernel<<<B, 512, 0, stream>>>(x, head_W, head_b, (float*)d_out);
}

// Round 4
// 1346.534 us; speedup vs baseline: 8.9074x; 2.6807x over previous
//
#include <hip/hip_runtime.h>
#include <hip/hip_bf16.h>
#include <math.h>

#define B 16
#define S 511
#define F 128
#define D 512
#define H 8
#define NB 6
#define DH 64
#define MLPD 2048
#define T 512
#define EPS 1e-5f

typedef unsigned short ushort;
typedef __attribute__((ext_vector_type(8))) short short8;
typedef __attribute__((ext_vector_type(4))) float floatx4;

__device__ __forceinline__ ushort f2bf(float f) {
    union { float f; unsigned u; } cv; cv.f = f;
    unsigned r = (cv.u + 0x7fff + ((cv.u >> 16) & 1)) >> 16;  // RNE
    return (ushort)r;
}

// ---------------- embed ----------------
__global__ void embed_kernel(const float* __restrict__ src,
                             const float* __restrict__ emb_W,
                             const float* __restrict__ emb_b,
                             const float* __restrict__ cls_tok,
                             float* __restrict__ x) {
    int row = blockIdx.x;          // b*T + t
    int b = row / T, t = row % T;
    int tid = threadIdx.x;         // 256
    __shared__ float sv[F];
    if (t > 0) {
        if (tid < F) sv[tid] = src[(b * S + (t - 1)) * F + tid];
    }
    __syncthreads();
    const float LOG1E4 = 9.210340371976184f;
    #pragma unroll
    for (int l = 0; l < 2; ++l) {
        int d = tid + l * 256;
        float je = (float)(d & ~1);
        float ang = (float)t * expf(-(je / (float)D) * LOG1E4);
        float pe = (d & 1) ? cosf(ang) : sinf(ang);
        float val;
        if (t == 0) {
            val = cls_tok[d];
        } else {
            float acc = emb_b[d];
            #pragma unroll 8
            for (int f = 0; f < F; ++f) acc += sv[f] * emb_W[f * D + d];
            val = acc;
        }
        x[row * D + d] = val + pe;
    }
}

// ---------------- layernorm -> bf16 ----------------
__global__ void ln_kernel(const float* __restrict__ xin,
                          const float* __restrict__ g,
                          const float* __restrict__ bb,
                          ushort* __restrict__ out) {
    int row = blockIdx.x;
    int tid = threadIdx.x;  // 256
    float v0 = xin[row * D + tid];
    float v1 = xin[row * D + tid + 256];
    float s = v0 + v1;
    __shared__ float red[4];
    __shared__ float red2[4];
    #pragma unroll
    for (int off = 32; off > 0; off >>= 1) s += __shfl_down(s, off, 64);
    if ((tid & 63) == 0) red[tid >> 6] = s;
    __syncthreads();
    if (tid == 0) red[0] = (red[0] + red[1] + red[2] + red[3]) * (1.0f / (float)D);
    __syncthreads();
    float mean = red[0];
    float d0 = v0 - mean, d1 = v1 - mean;
    float sq = d0 * d0 + d1 * d1;
    #pragma unroll
    for (int off = 32; off > 0; off >>= 1) sq += __shfl_down(sq, off, 64);
    if ((tid & 63) == 0) red2[tid >> 6] = sq;
    __syncthreads();
    if (tid == 0) red2[0] = rsqrtf((red2[0] + red2[1] + red2[2] + red2[3]) * (1.0f / (float)D) + EPS);
    __syncthreads();
    float rstd = red2[0];
    out[row * D + tid]       = f2bf(d0 * rstd * g[tid] + bb[tid]);
    out[row * D + tid + 256] = f2bf(d1 * rstd * g[tid + 256] + bb[tid + 256]);
}

// ---------------- qkv weight transpose+cast: W[mat][64d][64e] f32 -> WT[mat][64e][64d] bf16 ----------------
__global__ void wtransq_kernel(const float* __restrict__ Wq, const float* __restrict__ Wk,
                               const float* __restrict__ Wv,
                               ushort* __restrict__ WqT, ushort* __restrict__ WkT,
                               ushort* __restrict__ WvT) {
    int mat = blockIdx.x;          // 0..NB*H-1
    int which = blockIdx.y;        // 0,1,2
    const float* W = (which == 0 ? Wq : which == 1 ? Wk : Wv) + (size_t)mat * 4096;
    ushort* O = (which == 0 ? WqT : which == 1 ? WkT : WvT) + (size_t)mat * 4096;
    __shared__ float t[64][65];
    int tid = threadIdx.x;  // 256
    int r0 = tid >> 6, c = tid & 63;
    #pragma unroll
    for (int l = 0; l < 16; ++l) {
        int row = r0 * 16 + l;
        t[row][c] = W[row * 64 + c];
    }
    __syncthreads();
    #pragma unroll
    for (int l = 0; l < 16; ++l) {
        int row = r0 * 16 + l;       // output row = e
        O[row * 64 + c] = f2bf(t[c][row]);
    }
}

// ---------------- QKV: per-head MFMA GEMM ----------------
// grid (BT/128, H), block 256 (4 waves). Wave w: rows m0+w*32..+31 (2 m-frags).
// q,k out: [bh][t][dh] bf16; v out transposed: vT [bh][dh][t] bf16.
__global__ __launch_bounds__(256) void qkv_kernel(
        const ushort* __restrict__ hb,
        const ushort* __restrict__ WqT, const float* __restrict__ bq,
        const ushort* __restrict__ WkT, const float* __restrict__ bk,
        const ushort* __restrict__ WvT, const float* __restrict__ bv,
        ushort* __restrict__ qo, ushort* __restrict__ ko, ushort* __restrict__ vTo) {
    int m0 = blockIdx.x * 128;
    int hh = blockIdx.y;
    int tid = threadIdx.x;
    int lane = tid & 63;
    int w = __builtin_amdgcn_readfirstlane(tid >> 6);
    int quad = lane >> 4, l15 = lane & 15;

    // A fragments straight from global (bf16 ln1 out), rows stride D
    short8 af[2][2];
    #pragma unroll
    for (int mt = 0; mt < 2; ++mt) {
        const ushort* ab = hb + (size_t)(m0 + w * 32 + mt * 16 + l15) * D + hh * DH + quad * 8;
        af[mt][0] = *(const short8*)(ab);
        af[mt][1] = *(const short8*)(ab + 32);
    }

    floatx4 acc[3][2][4];
    #pragma unroll
    for (int xo = 0; xo < 3; ++xo)
        #pragma unroll
        for (int mt = 0; mt < 2; ++mt)
            #pragma unroll
            for (int nt = 0; nt < 4; ++nt) acc[xo][mt][nt] = (floatx4)0.f;

    #pragma unroll
    for (int xo = 0; xo < 3; ++xo) {
        const ushort* WT = (xo == 0 ? WqT : xo == 1 ? WkT : WvT) + (size_t)hh * 4096;
        #pragma unroll
        for (int nt = 0; nt < 4; ++nt) {
            const ushort* wb = WT + (size_t)(nt * 16 + l15) * 64 + quad * 8;
            short8 bf0 = *(const short8*)(wb);
            short8 bf1 = *(const short8*)(wb + 32);
            #pragma unroll
            for (int mt = 0; mt < 2; ++mt) {
                acc[xo][mt][nt] = __builtin_amdgcn_mfma_f32_16x16x32_bf16(af[mt][0], bf0, acc[xo][mt][nt], 0, 0, 0);
                acc[xo][mt][nt] = __builtin_amdgcn_mfma_f32_16x16x32_bf16(af[mt][1], bf1, acc[xo][mt][nt], 0, 0, 0);
            }
        }
    }

    int bb = m0 >> 9;              // batch (128-row tile never crosses batch: 512%128==0)
    int bh = bb * H + hh;
    #pragma unroll
    for (int mt = 0; mt < 2; ++mt) {
        int trow = m0 + w * 32 + mt * 16 + quad * 4;
        int tt = trow & (T - 1);
        #pragma unroll
        for (int nt = 0; nt < 4; ++nt) {
            int col = nt * 16 + l15;
            float bqv = bq[hh * DH + col];
            float bkv = bk[hh * DH + col];
            float bvv = bv[hh * DH + col];
            #pragma unroll
            for (int reg = 0; reg < 4; ++reg) {
                qo[((size_t)bh * T + tt + reg) * DH + col] = f2bf(acc[0][mt][nt][reg] + bqv);
                ko[((size_t)bh * T + tt + reg) * DH + col] = f2bf(acc[1][mt][nt][reg] + bkv);
                vTo[((size_t)bh * DH + col) * T + tt + reg] = f2bf(acc[2][mt][nt][reg] + bvv);
            }
        }
    }
}

// ---------------- MFMA flash attention ----------------
// grid (T/64, B*H), block 256 = 4 independent waves (16 q-rows each). No __syncthreads.
// Q/K/V fragments loaded directly from global (L2-hot). P round-trips per-wave LDS.
#define PSTRIDE 88   // ushorts: 176B rows -> 16B-aligned b128 reads, 2-way-max bank alias
__global__ __launch_bounds__(256) void attn_kernel(const ushort* __restrict__ q,
                                                   const ushort* __restrict__ k,
                                                   const ushort* __restrict__ vT,
                                                   float* __restrict__ x) {
    int qt = blockIdx.x;       // 0..7
    int bh = blockIdx.y;       // b*H + h
    int b = bh >> 3, hh = bh & 7;
    int tid = threadIdx.x;
    int lane = tid & 63;
    int w = __builtin_amdgcn_readfirstlane(tid >> 6);
    int quad = lane >> 4, l15 = lane & 15;

    __shared__ ushort Ps[4][16 * PSTRIDE];
    ushort* Pw = Ps[w];

    // Q A-fragments (held all loop): rows qt*64 + w*16 + l15
    const ushort* qbase = q + ((size_t)bh * T + qt * 64 + w * 16 + l15) * DH + quad * 8;
    short8 Qf0 = *(const short8*)(qbase);
    short8 Qf1 = *(const short8*)(qbase + 32);

    const ushort* kbase = k + (size_t)bh * T * DH;
    const ushort* vbase = vT + (size_t)bh * DH * T;

    float m_i[4] = {-1e30f, -1e30f, -1e30f, -1e30f};
    float l_i[4] = {0.f, 0.f, 0.f, 0.f};
    floatx4 O[4];
    #pragma unroll
    for (int j = 0; j < 4; ++j) O[j] = (floatx4)0.f;

    for (int kt = 0; kt < T / 64; ++kt) {
        // ---- S = (Q K^T) * scale, C-layout: row(q)=quad*4+reg, col(key)=j*16+l15 ----
        floatx4 sc[4];
        #pragma unroll
        for (int j = 0; j < 4; ++j) {
            const ushort* kr = kbase + (size_t)(kt * 64 + j * 16 + l15) * DH + quad * 8;
            short8 kf0 = *(const short8*)(kr);
            short8 kf1 = *(const short8*)(kr + 32);
            floatx4 s4 = (floatx4)0.f;
            s4 = __builtin_amdgcn_mfma_f32_16x16x32_bf16(Qf0, kf0, s4, 0, 0, 0);
            s4 = __builtin_amdgcn_mfma_f32_16x16x32_bf16(Qf1, kf1, s4, 0, 0, 0);
            #pragma unroll
            for (int r = 0; r < 4; ++r) s4[r] *= 0.125f;
            sc[j] = s4;
        }
        // ---- online softmax (per q-row = per (quad,reg); cols live on 16 lanes) ----
        float mn[4], alpha[4];
        #pragma unroll
        for (int r = 0; r < 4; ++r) {
            float mx = fmaxf(fmaxf(sc[0][r], sc[1][r]), fmaxf(sc[2][r], sc[3][r]));
            mx = fmaxf(mx, __shfl_xor(mx, 1));
            mx = fmaxf(mx, __shfl_xor(mx, 2));
            mx = fmaxf(mx, __shfl_xor(mx, 4));
            mx = fmaxf(mx, __shfl_xor(mx, 8));
            mn[r] = fmaxf(m_i[r], mx);
            alpha[r] = __expf(m_i[r] - mn[r]);
            m_i[r] = mn[r];
        }
        float psum[4] = {0.f, 0.f, 0.f, 0.f};
        #pragma unroll
        for (int j = 0; j < 4; ++j) {
            #pragma unroll
            for (int r = 0; r < 4; ++r) {
                float p = __expf(sc[j][r] - mn[r]);
                ushort pb = f2bf(p);
                union { unsigned u; float f; } cv; cv.u = ((unsigned)pb) << 16;
                psum[r] += cv.f;                      // sum the bf16-rounded value (consistent with PV)
                Pw[(quad * 4 + r) * PSTRIDE + j * 16 + l15] = pb;
            }
        }
        #pragma unroll
        for (int r = 0; r < 4; ++r) {
            psum[r] += __shfl_xor(psum[r], 1);
            psum[r] += __shfl_xor(psum[r], 2);
            psum[r] += __shfl_xor(psum[r], 4);
            psum[r] += __shfl_xor(psum[r], 8);
            l_i[r] = l_i[r] * alpha[r] + psum[r];
        }
        #pragma unroll
        for (int j = 0; j < 4; ++j)
            #pragma unroll
            for (int r = 0; r < 4; ++r) O[j][r] *= alpha[r];

        // ---- PV: O[q][dh] += P[q][key] * V[key][dh]  (A = P from LDS, B = vT rows) ----
        short8 af0 = *(const short8*)&Pw[l15 * PSTRIDE + quad * 8];
        short8 af1 = *(const short8*)&Pw[l15 * PSTRIDE + 32 + quad * 8];
        #pragma unroll
        for (int j = 0; j < 4; ++j) {
            const ushort* vr = vbase + (size_t)(j * 16 + l15) * T + kt * 64 + quad * 8;
            short8 vf0 = *(const short8*)(vr);
            short8 vf1 = *(const short8*)(vr + 32);
            O[j] = __builtin_amdgcn_mfma_f32_16x16x32_bf16(af0, vf0, O[j], 0, 0, 0);
            O[j] = __builtin_amdgcn_mfma_f32_16x16x32_bf16(af1, vf1, O[j], 0, 0, 0);
        }
    }

    // ---- epilogue: residual add into x (fp32) ----
    #pragma unroll
    for (int r = 0; r < 4; ++r) {
        float rl = 1.0f / l_i[r];
        int row = b * T + qt * 64 + w * 16 + quad * 4 + r;
        #pragma unroll
        for (int j = 0; j < 4; ++j) {
            x[(size_t)row * D + hh * DH + j * 16 + l15] += O[j][r] * rl;
        }
    }
}

// ---------------- MLP weight transpose+cast ----------------
__global__ void wtrans_kernel(const float* __restrict__ W,
                              ushort* __restrict__ Wt,
                              int K, int N) {
    int kb = blockIdx.x * 32, nb = blockIdx.y * 32, mat = blockIdx.z;
    __shared__ float tile[32][33];
    int tid = threadIdx.x; // 256
    int c = tid & 31, r0 = tid >> 5;
    const float* Wm = W + (size_t)mat * K * N;
    ushort* Wtm = Wt + (size_t)mat * K * N;
    #pragma unroll
    for (int l = 0; l < 4; ++l) {
        int r = r0 + l * 8;
        tile[r][c] = Wm[(size_t)(kb + r) * N + nb + c];
    }
    __syncthreads();
    #pragma unroll
    for (int l = 0; l < 4; ++l) {
        int r = r0 + l * 8;
        Wtm[(size_t)(nb + r) * K + kb + c] = f2bf(tile[c][r]);
    }
}

// ---------------- MFMA GEMM (m97 structure): C = A[M,K] @ Bt[N,K]^T ----------------
__device__ __forceinline__ void gload_lds16(const ushort* g, ushort* l) {
    __builtin_amdgcn_global_load_lds((const __attribute__((address_space(1))) unsigned int*)g,
                                     (__attribute__((address_space(3))) unsigned int*)l,
                                     16, 0, 0);
}

template<int MODE>
__global__ __launch_bounds__(256) void mfma_gemm(const ushort* __restrict__ A,
                                                 const ushort* __restrict__ Bt,
                                                 const float* __restrict__ bias,
                                                 void* __restrict__ Cv,
                                                 int M, int N, int K) {
    __shared__ ushort As[128 * 32];
    __shared__ ushort Bs[128 * 32];
    int tid = threadIdx.x;
    int lane = tid & 63;
    int w = __builtin_amdgcn_readfirstlane(tid >> 6);
    int wr = (w >> 1) * 64, wc = (w & 1) * 64;
    int m0 = blockIdx.x * 128, n0 = blockIdx.y * 128;

    floatx4 acc[4][4];
    #pragma unroll
    for (int i = 0; i < 4; ++i)
        #pragma unroll
        for (int j = 0; j < 4; ++j) acc[i][j] = (floatx4)0.f;

    int lrow = lane >> 2;
    int lk = (lane & 3) * 8;
    const ushort* Ag = A + (size_t)(m0 + 32 * w + lrow) * K + lk;
    const ushort* Bg = Bt + (size_t)(n0 + 32 * w + lrow) * K + lk;
    ushort* AsW = &As[(32 * w) * 32];
    ushort* BsW = &Bs[(32 * w) * 32];

    int fa = (lane & 15) * 32 + (lane >> 4) * 8;

    for (int kt = 0; kt < K; kt += 32) {
        gload_lds16(Ag + kt, AsW);
        gload_lds16(Ag + kt + (size_t)16 * K, AsW + 16 * 32);
        gload_lds16(Bg + kt, BsW);
        gload_lds16(Bg + kt + (size_t)16 * K, BsW + 16 * 32);
        __syncthreads();

        short8 af[4], bf[4];
        #pragma unroll
        for (int i = 0; i < 4; ++i) af[i] = *(const short8*)&As[(wr + 16 * i) * 32 + fa];
        #pragma unroll
        for (int j = 0; j < 4; ++j) bf[j] = *(const short8*)&Bs[(wc + 16 * j) * 32 + fa];
        #pragma unroll
        for (int i = 0; i < 4; ++i)
            #pragma unroll
            for (int j = 0; j < 4; ++j)
                acc[i][j] = __builtin_amdgcn_mfma_f32_16x16x32_bf16(af[i], bf[j], acc[i][j], 0, 0, 0);
        __syncthreads();
    }

    int rbase = (lane >> 4) * 4;
    int cidx = lane & 15;
    if (MODE == 0) {
        ushort* C = (ushort*)Cv;
        #pragma unroll
        for (int i = 0; i < 4; ++i) {
            #pragma unroll
            for (int j = 0; j < 4; ++j) {
                int gc = n0 + wc + 16 * j + cidx;
                float bv = bias[gc];
                int gr = m0 + wr + 16 * i + rbase;
                #pragma unroll
                for (int reg = 0; reg < 4; ++reg) {
                    float val = acc[i][j][reg] + bv;
                    val = 0.5f * val * (1.0f + erff(val * 0.70710678118f));
                    C[(size_t)(gr + reg) * N + gc] = f2bf(val);
                }
            }
        }
    } else {
        float* C = (float*)Cv;
        #pragma unroll
        for (int i = 0; i < 4; ++i) {
            #pragma unroll
            for (int j = 0; j < 4; ++j) {
                int gc = n0 + wc + 16 * j + cidx;
                float bv = bias[gc];
                int gr = m0 + wr + 16 * i + rbase;
                #pragma unroll
                for (int reg = 0; reg < 4; ++reg) {
                    C[(size_t)(gr + reg) * N + gc] += acc[i][j][reg] + bv;
                }
            }
        }
    }
}

// ---------------- head ----------------
__global__ void head_kernel(const float* __restrict__ x,
                            const float* __restrict__ hw,
                            const float* __restrict__ hb,
                            float* __restrict__ out) {
    int b = blockIdx.x;
    int tid = threadIdx.x; // 512
    float s = x[(size_t)b * T * D + tid] * hw[tid];
    #pragma unroll
    for (int off = 32; off > 0; off >>= 1) s += __shfl_down(s, off, 64);
    __shared__ float red[8];
    if ((tid & 63) == 0) red[tid >> 6] = s;
    __syncthreads();
    if (tid == 0) {
        float t = 0.f;
        #pragma unroll
        for (int i = 0; i < 8; ++i) t += red[i];
        out[b] = 1.0f / (1.0f + __expf(-(t + hb[0])));
    }
}

extern "C" void kernel_launch(void* const* d_in, const int* in_sizes, int n_in,
                              void* d_out, int out_size, void* d_ws, size_t ws_size,
                              hipStream_t stream) {
    const float* src     = (const float*)d_in[0];
    const float* emb_W   = (const float*)d_in[1];
    const float* emb_b   = (const float*)d_in[2];
    const float* cls_tok = (const float*)d_in[3];
    const float* ln1_g   = (const float*)d_in[4];
    const float* ln1_b   = (const float*)d_in[5];
    const float* Wq      = (const float*)d_in[6];
    const float* bq      = (const float*)d_in[7];
    const float* Wk      = (const float*)d_in[8];
    const float* bk      = (const float*)d_in[9];
    const float* Wv      = (const float*)d_in[10];
    const float* bv      = (const float*)d_in[11];
    const float* ln2_g   = (const float*)d_in[12];
    const float* ln2_b   = (const float*)d_in[13];
    const float* W1      = (const float*)d_in[14];
    const float* b1      = (const float*)d_in[15];
    const float* W2      = (const float*)d_in[16];
    const float* b2      = (const float*)d_in[17];
    const float* head_W  = (const float*)d_in[18];
    const float* head_b  = (const float*)d_in[19];

    const size_t NTOK = (size_t)B * T;          // 8192
    char* wsb = (char*)d_ws;
    float*  x    = (float*)wsb;      wsb += NTOK * D * 4;
    ushort* hbuf = (ushort*)wsb;     wsb += NTOK * D * 2;
    ushort* q    = (ushort*)wsb;     wsb += NTOK * D * 2;
    ushort* k    = (ushort*)wsb;     wsb += NTOK * D * 2;
    ushort* vT   = (ushort*)wsb;     wsb += NTOK * D * 2;
    ushort* u    = (ushort*)wsb;     wsb += NTOK * MLPD * 2;
    ushort* W1t  = (ushort*)wsb;     wsb += (size_t)NB * D * MLPD * 2;
    ushort* W2t  = (ushort*)wsb;     wsb += (size_t)NB * D * MLPD * 2;
    ushort* WqT  = (ushort*)wsb;     wsb += (size_t)NB * H * DH * DH * 2;
    ushort* WkT  = (ushort*)wsb;     wsb += (size_t)NB * H * DH * DH * 2;
    ushort* WvT  = (ushort*)wsb;     wsb += (size_t)NB * H * DH * DH * 2;

    // weight prep (every launch)
    wtrans_kernel<<<dim3(D / 32, MLPD / 32, NB), 256, 0, stream>>>(W1, W1t, D, MLPD);
    wtrans_kernel<<<dim3(MLPD / 32, D / 32, NB), 256, 0, stream>>>(W2, W2t, MLPD, D);
    wtransq_kernel<<<dim3(NB * H, 3), 256, 0, stream>>>(Wq, Wk, Wv, WqT, WkT, WvT);

    embed_kernel<<<B * T, 256, 0, stream>>>(src, emb_W, emb_b, cls_tok, x);

    for (int i = 0; i < NB; ++i) {
        ln_kernel<<<B * T, 256, 0, stream>>>(x, ln1_g + i * D, ln1_b + i * D, hbuf);
        qkv_kernel<<<dim3(B * T / 128, H), 256, 0, stream>>>(hbuf,
            WqT + (size_t)i * H * DH * DH, bq + (size_t)i * H * DH,
            WkT + (size_t)i * H * DH * DH, bk + (size_t)i * H * DH,
            WvT + (size_t)i * H * DH * DH, bv + (size_t)i * H * DH,
            q, k, vT);
        attn_kernel<<<dim3(T / 64, B * H), 256, 0, stream>>>(q, k, vT, x);
        ln_kernel<<<B * T, 256, 0, stream>>>(x, ln2_g + i * D, ln2_b + i * D, hbuf);
        mfma_gemm<0><<<dim3(B * T / 128, MLPD / 128), 256, 0, stream>>>(
            hbuf, W1t + (size_t)i * D * MLPD, b1 + (size_t)i * MLPD, u, B * T, MLPD, D);
        mfma_gemm<1><<<dim3(B * T / 128, D / 128), 256, 0, stream>>>(
            u, W2t + (size_t)i * MLPD * D, b2 + (size_t)i * D, x, B * T, D, MLPD);
    }

    head_kernel<<<B, 512, 0, stream>>>(x, head_W, head_b, (float*)d_out);
}

// Round 5
// 1251.114 us; speedup vs baseline: 9.5867x; 1.0763x over previous
//
#include <hip/hip_runtime.h>
#include <hip/hip_bf16.h>
#include <math.h>

#define B 16
#define S 511
#define F 128
#define D 512
#define H 8
#define NB 6
#define DH 64
#define MLPD 2048
#define T 512
#define EPS 1e-5f

typedef unsigned short ushort;
typedef __attribute__((ext_vector_type(8))) short short8;
typedef __attribute__((ext_vector_type(4))) float floatx4;

__device__ __forceinline__ ushort f2bf(float f) {
    union { float f; unsigned u; } cv; cv.f = f;
    unsigned r = (cv.u + 0x7fff + ((cv.u >> 16) & 1)) >> 16;  // RNE
    return (ushort)r;
}

// ---------------- cast src -> bf16 A-matrix for embed GEMM (t=0 rows zeroed) ----------------
__global__ void castsrc_kernel(const float* __restrict__ src, ushort* __restrict__ srcb) {
    int row = blockIdx.x;              // b*T + t
    int t = row & (T - 1), b = row >> 9;
    int tid = threadIdx.x;             // 128
    ushort v = 0;
    if (t > 0) v = f2bf(src[((size_t)b * S + (t - 1)) * F + tid]);
    srcb[(size_t)row * F + tid] = v;
}

// ---------------- generic transpose+cast: W [mat,K,N] fp32 -> Wt [mat,N,K] bf16 ----------------
__global__ void wtrans_kernel(const float* __restrict__ W,
                              ushort* __restrict__ Wt,
                              int K, int N) {
    int kb = blockIdx.x * 32, nb = blockIdx.y * 32, mat = blockIdx.z;
    __shared__ float tile[32][33];
    int tid = threadIdx.x; // 256
    int c = tid & 31, r0 = tid >> 5;
    const float* Wm = W + (size_t)mat * K * N;
    ushort* Wtm = Wt + (size_t)mat * K * N;
    #pragma unroll
    for (int l = 0; l < 4; ++l) {
        int r = r0 + l * 8;
        tile[r][c] = Wm[(size_t)(kb + r) * N + nb + c];
    }
    __syncthreads();
    #pragma unroll
    for (int l = 0; l < 4; ++l) {
        int r = r0 + l * 8;
        Wtm[(size_t)(nb + r) * K + kb + c] = f2bf(tile[c][r]);
    }
}

// ---------------- qkv weight transpose+cast ----------------
__global__ void wtransq_kernel(const float* __restrict__ Wq, const float* __restrict__ Wk,
                               const float* __restrict__ Wv,
                               ushort* __restrict__ WqT, ushort* __restrict__ WkT,
                               ushort* __restrict__ WvT) {
    int mat = blockIdx.x;          // 0..NB*H-1
    int which = blockIdx.y;        // 0,1,2
    const float* W = (which == 0 ? Wq : which == 1 ? Wk : Wv) + (size_t)mat * 4096;
    ushort* O = (which == 0 ? WqT : which == 1 ? WkT : WvT) + (size_t)mat * 4096;
    __shared__ float t[64][65];
    int tid = threadIdx.x;  // 256
    int r0 = tid >> 6, c = tid & 63;
    #pragma unroll
    for (int l = 0; l < 16; ++l) {
        int row = r0 * 16 + l;
        t[row][c] = W[row * 64 + c];
    }
    __syncthreads();
    #pragma unroll
    for (int l = 0; l < 16; ++l) {
        int row = r0 * 16 + l;
        O[row * 64 + c] = f2bf(t[c][row]);
    }
}

// ---------------- async global->LDS helper ----------------
__device__ __forceinline__ void gload_lds16(const ushort* g, ushort* l) {
    __builtin_amdgcn_global_load_lds((const __attribute__((address_space(1))) unsigned int*)g,
                                     (__attribute__((address_space(3))) unsigned int*)l,
                                     16, 0, 0);
}

// ---------------- embed GEMM: x = concat(cls, srcb@embWt^T)+emb_b+pe, fp32 out ----------------
// M=B*T, N=D, K=F. tile 128x128, BK=32, 4 K-iters.
__global__ __launch_bounds__(256) void embed_gemm(const ushort* __restrict__ A,
                                                  const ushort* __restrict__ Bt,
                                                  const float* __restrict__ emb_b,
                                                  const float* __restrict__ cls_tok,
                                                  float* __restrict__ x) {
    __shared__ ushort As[128 * 32];
    __shared__ ushort Bs[128 * 32];
    int tid = threadIdx.x;
    int lane = tid & 63;
    int w = __builtin_amdgcn_readfirstlane(tid >> 6);
    int wr = (w >> 1) * 64, wc = (w & 1) * 64;
    int m0 = blockIdx.x * 128, n0 = blockIdx.y * 128;

    floatx4 acc[4][4];
    #pragma unroll
    for (int i = 0; i < 4; ++i)
        #pragma unroll
        for (int j = 0; j < 4; ++j) acc[i][j] = (floatx4)0.f;

    int lrow = lane >> 2;
    int lk = (lane & 3) * 8;
    const ushort* Ag = A + (size_t)(m0 + 32 * w + lrow) * F + lk;
    const ushort* Bg = Bt + (size_t)(n0 + 32 * w + lrow) * F + lk;
    ushort* AsW = &As[(32 * w) * 32];
    ushort* BsW = &Bs[(32 * w) * 32];
    int fa = (lane & 15) * 32 + (lane >> 4) * 8;

    for (int kt = 0; kt < F; kt += 32) {
        gload_lds16(Ag + kt, AsW);
        gload_lds16(Ag + kt + (size_t)16 * F, AsW + 16 * 32);
        gload_lds16(Bg + kt, BsW);
        gload_lds16(Bg + kt + (size_t)16 * F, BsW + 16 * 32);
        __syncthreads();
        short8 af[4], bf[4];
        #pragma unroll
        for (int i = 0; i < 4; ++i) af[i] = *(const short8*)&As[(wr + 16 * i) * 32 + fa];
        #pragma unroll
        for (int j = 0; j < 4; ++j) bf[j] = *(const short8*)&Bs[(wc + 16 * j) * 32 + fa];
        #pragma unroll
        for (int i = 0; i < 4; ++i)
            #pragma unroll
            for (int j = 0; j < 4; ++j)
                acc[i][j] = __builtin_amdgcn_mfma_f32_16x16x32_bf16(af[i], bf[j], acc[i][j], 0, 0, 0);
        __syncthreads();
    }

    const float LOG1E4 = 9.210340371976184f;
    int rbase = (lane >> 4) * 4;
    int cidx = lane & 15;
    #pragma unroll
    for (int j = 0; j < 4; ++j) {
        int gc = n0 + wc + 16 * j + cidx;               // global dim d
        float je = (float)(gc & ~1);
        float freq = expf(-(je / (float)D) * LOG1E4);
        float ebv = emb_b[gc];
        float clsv = cls_tok[gc];
        bool odd = (gc & 1);
        #pragma unroll
        for (int i = 0; i < 4; ++i) {
            int gr = m0 + wr + 16 * i + rbase;
            #pragma unroll
            for (int reg = 0; reg < 4; ++reg) {
                int row = gr + reg;
                int t = row & (T - 1);
                float ang = (float)t * freq;
                float pe = odd ? cosf(ang) : sinf(ang);
                float val = (t == 0) ? (clsv + pe) : (acc[i][j][reg] + ebv + pe);
                x[(size_t)row * D + gc] = val;
            }
        }
    }
}

// ---------------- layernorm -> bf16: one wave per row, shuffle-only ----------------
__global__ __launch_bounds__(256) void ln_kernel(const float* __restrict__ xin,
                                                 const float* __restrict__ g,
                                                 const float* __restrict__ bb,
                                                 ushort* __restrict__ out) {
    int lane = threadIdx.x & 63;
    int row = blockIdx.x * 4 + (threadIdx.x >> 6);
    const float* xr = xin + (size_t)row * D + lane * 8;
    float4 a0 = *(const float4*)xr;
    float4 a1 = *(const float4*)(xr + 4);
    float s = a0.x + a0.y + a0.z + a0.w + a1.x + a1.y + a1.z + a1.w;
    #pragma unroll
    for (int off = 1; off < 64; off <<= 1) s += __shfl_xor(s, off);
    float mean = s * (1.0f / (float)D);
    float d0 = a0.x - mean, d1 = a0.y - mean, d2 = a0.z - mean, d3 = a0.w - mean;
    float d4 = a1.x - mean, d5 = a1.y - mean, d6 = a1.z - mean, d7 = a1.w - mean;
    float sq = d0*d0 + d1*d1 + d2*d2 + d3*d3 + d4*d4 + d5*d5 + d6*d6 + d7*d7;
    #pragma unroll
    for (int off = 1; off < 64; off <<= 1) sq += __shfl_xor(sq, off);
    float rstd = rsqrtf(sq * (1.0f / (float)D) + EPS);
    const float* gp = g + lane * 8;
    const float* bp = bb + lane * 8;
    float4 g0 = *(const float4*)gp, g1 = *(const float4*)(gp + 4);
    float4 b0 = *(const float4*)bp, b1 = *(const float4*)(bp + 4);
    short8 o;
    o[0] = (short)f2bf(d0 * rstd * g0.x + b0.x);
    o[1] = (short)f2bf(d1 * rstd * g0.y + b0.y);
    o[2] = (short)f2bf(d2 * rstd * g0.z + b0.z);
    o[3] = (short)f2bf(d3 * rstd * g0.w + b0.w);
    o[4] = (short)f2bf(d4 * rstd * g1.x + b1.x);
    o[5] = (short)f2bf(d5 * rstd * g1.y + b1.y);
    o[6] = (short)f2bf(d6 * rstd * g1.z + b1.z);
    o[7] = (short)f2bf(d7 * rstd * g1.w + b1.w);
    *(short8*)(out + (size_t)row * D + lane * 8) = o;
}

// ---------------- QKV: per-head MFMA GEMM ----------------
__global__ __launch_bounds__(256) void qkv_kernel(
        const ushort* __restrict__ hb,
        const ushort* __restrict__ WqT, const float* __restrict__ bq,
        const ushort* __restrict__ WkT, const float* __restrict__ bk,
        const ushort* __restrict__ WvT, const float* __restrict__ bv,
        ushort* __restrict__ qo, ushort* __restrict__ ko, ushort* __restrict__ vTo) {
    int m0 = blockIdx.x * 128;
    int hh = blockIdx.y;
    int tid = threadIdx.x;
    int lane = tid & 63;
    int w = __builtin_amdgcn_readfirstlane(tid >> 6);
    int quad = lane >> 4, l15 = lane & 15;

    short8 af[2][2];
    #pragma unroll
    for (int mt = 0; mt < 2; ++mt) {
        const ushort* ab = hb + (size_t)(m0 + w * 32 + mt * 16 + l15) * D + hh * DH + quad * 8;
        af[mt][0] = *(const short8*)(ab);
        af[mt][1] = *(const short8*)(ab + 32);
    }

    floatx4 acc[3][2][4];
    #pragma unroll
    for (int xo = 0; xo < 3; ++xo)
        #pragma unroll
        for (int mt = 0; mt < 2; ++mt)
            #pragma unroll
            for (int nt = 0; nt < 4; ++nt) acc[xo][mt][nt] = (floatx4)0.f;

    #pragma unroll
    for (int xo = 0; xo < 3; ++xo) {
        const ushort* WT = (xo == 0 ? WqT : xo == 1 ? WkT : WvT) + (size_t)hh * 4096;
        #pragma unroll
        for (int nt = 0; nt < 4; ++nt) {
            const ushort* wb = WT + (size_t)(nt * 16 + l15) * 64 + quad * 8;
            short8 bf0 = *(const short8*)(wb);
            short8 bf1 = *(const short8*)(wb + 32);
            #pragma unroll
            for (int mt = 0; mt < 2; ++mt) {
                acc[xo][mt][nt] = __builtin_amdgcn_mfma_f32_16x16x32_bf16(af[mt][0], bf0, acc[xo][mt][nt], 0, 0, 0);
                acc[xo][mt][nt] = __builtin_amdgcn_mfma_f32_16x16x32_bf16(af[mt][1], bf1, acc[xo][mt][nt], 0, 0, 0);
            }
        }
    }

    int bb = m0 >> 9;
    int bh = bb * H + hh;
    #pragma unroll
    for (int mt = 0; mt < 2; ++mt) {
        int trow = m0 + w * 32 + mt * 16 + quad * 4;
        int tt = trow & (T - 1);
        #pragma unroll
        for (int nt = 0; nt < 4; ++nt) {
            int col = nt * 16 + l15;
            float bqv = bq[hh * DH + col];
            float bkv = bk[hh * DH + col];
            float bvv = bv[hh * DH + col];
            #pragma unroll
            for (int reg = 0; reg < 4; ++reg) {
                qo[((size_t)bh * T + tt + reg) * DH + col] = f2bf(acc[0][mt][nt][reg] + bqv);
                ko[((size_t)bh * T + tt + reg) * DH + col] = f2bf(acc[1][mt][nt][reg] + bkv);
                vTo[((size_t)bh * DH + col) * T + tt + reg] = f2bf(acc[2][mt][nt][reg] + bvv);
            }
        }
    }
}

// ---------------- MFMA flash attention ----------------
#define PSTRIDE 88
__global__ __launch_bounds__(256) void attn_kernel(const ushort* __restrict__ q,
                                                   const ushort* __restrict__ k,
                                                   const ushort* __restrict__ vT,
                                                   float* __restrict__ x) {
    int qt = blockIdx.x;
    int bh = blockIdx.y;
    int b = bh >> 3, hh = bh & 7;
    int tid = threadIdx.x;
    int lane = tid & 63;
    int w = __builtin_amdgcn_readfirstlane(tid >> 6);
    int quad = lane >> 4, l15 = lane & 15;

    __shared__ ushort Ps[4][16 * PSTRIDE];
    ushort* Pw = Ps[w];

    const ushort* qbase = q + ((size_t)bh * T + qt * 64 + w * 16 + l15) * DH + quad * 8;
    short8 Qf0 = *(const short8*)(qbase);
    short8 Qf1 = *(const short8*)(qbase + 32);

    const ushort* kbase = k + (size_t)bh * T * DH;
    const ushort* vbase = vT + (size_t)bh * DH * T;

    float m_i[4] = {-1e30f, -1e30f, -1e30f, -1e30f};
    float l_i[4] = {0.f, 0.f, 0.f, 0.f};
    floatx4 O[4];
    #pragma unroll
    for (int j = 0; j < 4; ++j) O[j] = (floatx4)0.f;

    for (int kt = 0; kt < T / 64; ++kt) {
        floatx4 sc[4];
        #pragma unroll
        for (int j = 0; j < 4; ++j) {
            const ushort* kr = kbase + (size_t)(kt * 64 + j * 16 + l15) * DH + quad * 8;
            short8 kf0 = *(const short8*)(kr);
            short8 kf1 = *(const short8*)(kr + 32);
            floatx4 s4 = (floatx4)0.f;
            s4 = __builtin_amdgcn_mfma_f32_16x16x32_bf16(Qf0, kf0, s4, 0, 0, 0);
            s4 = __builtin_amdgcn_mfma_f32_16x16x32_bf16(Qf1, kf1, s4, 0, 0, 0);
            #pragma unroll
            for (int r = 0; r < 4; ++r) s4[r] *= 0.125f;
            sc[j] = s4;
        }
        float mn[4], alpha[4];
        #pragma unroll
        for (int r = 0; r < 4; ++r) {
            float mx = fmaxf(fmaxf(sc[0][r], sc[1][r]), fmaxf(sc[2][r], sc[3][r]));
            mx = fmaxf(mx, __shfl_xor(mx, 1));
            mx = fmaxf(mx, __shfl_xor(mx, 2));
            mx = fmaxf(mx, __shfl_xor(mx, 4));
            mx = fmaxf(mx, __shfl_xor(mx, 8));
            mn[r] = fmaxf(m_i[r], mx);
            alpha[r] = __expf(m_i[r] - mn[r]);
            m_i[r] = mn[r];
        }
        float psum[4] = {0.f, 0.f, 0.f, 0.f};
        #pragma unroll
        for (int j = 0; j < 4; ++j) {
            #pragma unroll
            for (int r = 0; r < 4; ++r) {
                float p = __expf(sc[j][r] - mn[r]);
                ushort pb = f2bf(p);
                union { unsigned u; float f; } cv; cv.u = ((unsigned)pb) << 16;
                psum[r] += cv.f;
                Pw[(quad * 4 + r) * PSTRIDE + j * 16 + l15] = pb;
            }
        }
        #pragma unroll
        for (int r = 0; r < 4; ++r) {
            psum[r] += __shfl_xor(psum[r], 1);
            psum[r] += __shfl_xor(psum[r], 2);
            psum[r] += __shfl_xor(psum[r], 4);
            psum[r] += __shfl_xor(psum[r], 8);
            l_i[r] = l_i[r] * alpha[r] + psum[r];
        }
        #pragma unroll
        for (int j = 0; j < 4; ++j)
            #pragma unroll
            for (int r = 0; r < 4; ++r) O[j][r] *= alpha[r];

        short8 af0 = *(const short8*)&Pw[l15 * PSTRIDE + quad * 8];
        short8 af1 = *(const short8*)&Pw[l15 * PSTRIDE + 32 + quad * 8];
        #pragma unroll
        for (int j = 0; j < 4; ++j) {
            const ushort* vr = vbase + (size_t)(j * 16 + l15) * T + kt * 64 + quad * 8;
            short8 vf0 = *(const short8*)(vr);
            short8 vf1 = *(const short8*)(vr + 32);
            O[j] = __builtin_amdgcn_mfma_f32_16x16x32_bf16(af0, vf0, O[j], 0, 0, 0);
            O[j] = __builtin_amdgcn_mfma_f32_16x16x32_bf16(af1, vf1, O[j], 0, 0, 0);
        }
    }

    #pragma unroll
    for (int r = 0; r < 4; ++r) {
        float rl = 1.0f / l_i[r];
        int row = b * T + qt * 64 + w * 16 + quad * 4 + r;
        #pragma unroll
        for (int j = 0; j < 4; ++j) {
            x[(size_t)row * D + hh * DH + j * 16 + l15] += O[j][r] * rl;
        }
    }
}

// ---------------- MFMA GEMM: C = A[M,K] @ Bt[N,K]^T ----------------
// MODE 0 (SPLIT=1): C(bf16) = gelu(acc+bias)   MODE 1 (SPLIT=2): C(fp32) atomicAdd acc (+bias on kz=0)
template<int MODE, int SPLIT>
__global__ __launch_bounds__(256) void mfma_gemm(const ushort* __restrict__ A,
                                                 const ushort* __restrict__ Bt,
                                                 const float* __restrict__ bias,
                                                 void* __restrict__ Cv,
                                                 int M, int N, int K) {
    __shared__ ushort As[128 * 32];
    __shared__ ushort Bs[128 * 32];
    int tid = threadIdx.x;
    int lane = tid & 63;
    int w = __builtin_amdgcn_readfirstlane(tid >> 6);
    int wr = (w >> 1) * 64, wc = (w & 1) * 64;
    int m0 = blockIdx.x * 128, n0 = blockIdx.y * 128;
    int kz = blockIdx.z;
    int kchunk = K / SPLIT;
    int k0 = kz * kchunk, k1 = k0 + kchunk;

    floatx4 acc[4][4];
    #pragma unroll
    for (int i = 0; i < 4; ++i)
        #pragma unroll
        for (int j = 0; j < 4; ++j) acc[i][j] = (floatx4)0.f;

    int lrow = lane >> 2;
    int lk = (lane & 3) * 8;
    const ushort* Ag = A + (size_t)(m0 + 32 * w + lrow) * K + lk;
    const ushort* Bg = Bt + (size_t)(n0 + 32 * w + lrow) * K + lk;
    ushort* AsW = &As[(32 * w) * 32];
    ushort* BsW = &Bs[(32 * w) * 32];
    int fa = (lane & 15) * 32 + (lane >> 4) * 8;

    for (int kt = k0; kt < k1; kt += 32) {
        gload_lds16(Ag + kt, AsW);
        gload_lds16(Ag + kt + (size_t)16 * K, AsW + 16 * 32);
        gload_lds16(Bg + kt, BsW);
        gload_lds16(Bg + kt + (size_t)16 * K, BsW + 16 * 32);
        __syncthreads();
        short8 af[4], bf[4];
        #pragma unroll
        for (int i = 0; i < 4; ++i) af[i] = *(const short8*)&As[(wr + 16 * i) * 32 + fa];
        #pragma unroll
        for (int j = 0; j < 4; ++j) bf[j] = *(const short8*)&Bs[(wc + 16 * j) * 32 + fa];
        #pragma unroll
        for (int i = 0; i < 4; ++i)
            #pragma unroll
            for (int j = 0; j < 4; ++j)
                acc[i][j] = __builtin_amdgcn_mfma_f32_16x16x32_bf16(af[i], bf[j], acc[i][j], 0, 0, 0);
        __syncthreads();
    }

    int rbase = (lane >> 4) * 4;
    int cidx = lane & 15;
    if (MODE == 0) {
        ushort* C = (ushort*)Cv;
        #pragma unroll
        for (int i = 0; i < 4; ++i) {
            #pragma unroll
            for (int j = 0; j < 4; ++j) {
                int gc = n0 + wc + 16 * j + cidx;
                float bv = bias[gc];
                int gr = m0 + wr + 16 * i + rbase;
                #pragma unroll
                for (int reg = 0; reg < 4; ++reg) {
                    float val = acc[i][j][reg] + bv;
                    val = 0.5f * val * (1.0f + erff(val * 0.70710678118f));
                    C[(size_t)(gr + reg) * N + gc] = f2bf(val);
                }
            }
        }
    } else {
        float* C = (float*)Cv;
        #pragma unroll
        for (int i = 0; i < 4; ++i) {
            #pragma unroll
            for (int j = 0; j < 4; ++j) {
                int gc = n0 + wc + 16 * j + cidx;
                float bv = (kz == 0) ? bias[gc] : 0.f;
                int gr = m0 + wr + 16 * i + rbase;
                #pragma unroll
                for (int reg = 0; reg < 4; ++reg) {
                    atomicAdd(&C[(size_t)(gr + reg) * N + gc], acc[i][j][reg] + bv);
                }
            }
        }
    }
}

// ---------------- head ----------------
__global__ void head_kernel(const float* __restrict__ x,
                            const float* __restrict__ hw,
                            const float* __restrict__ hb,
                            float* __restrict__ out) {
    int b = blockIdx.x;
    int tid = threadIdx.x; // 512
    float s = x[(size_t)b * T * D + tid] * hw[tid];
    #pragma unroll
    for (int off = 32; off > 0; off >>= 1) s += __shfl_down(s, off, 64);
    __shared__ float red[8];
    if ((tid & 63) == 0) red[tid >> 6] = s;
    __syncthreads();
    if (tid == 0) {
        float t = 0.f;
        #pragma unroll
        for (int i = 0; i < 8; ++i) t += red[i];
        out[b] = 1.0f / (1.0f + __expf(-(t + hb[0])));
    }
}

extern "C" void kernel_launch(void* const* d_in, const int* in_sizes, int n_in,
                              void* d_out, int out_size, void* d_ws, size_t ws_size,
                              hipStream_t stream) {
    const float* src     = (const float*)d_in[0];
    const float* emb_W   = (const float*)d_in[1];
    const float* emb_b   = (const float*)d_in[2];
    const float* cls_tok = (const float*)d_in[3];
    const float* ln1_g   = (const float*)d_in[4];
    const float* ln1_b   = (const float*)d_in[5];
    const float* Wq      = (const float*)d_in[6];
    const float* bq      = (const float*)d_in[7];
    const float* Wk      = (const float*)d_in[8];
    const float* bk      = (const float*)d_in[9];
    const float* Wv      = (const float*)d_in[10];
    const float* bv      = (const float*)d_in[11];
    const float* ln2_g   = (const float*)d_in[12];
    const float* ln2_b   = (const float*)d_in[13];
    const float* W1      = (const float*)d_in[14];
    const float* b1      = (const float*)d_in[15];
    const float* W2      = (const float*)d_in[16];
    const float* b2      = (const float*)d_in[17];
    const float* head_W  = (const float*)d_in[18];
    const float* head_b  = (const float*)d_in[19];

    const size_t NTOK = (size_t)B * T;          // 8192
    char* wsb = (char*)d_ws;
    float*  x    = (float*)wsb;      wsb += NTOK * D * 4;
    ushort* hbuf = (ushort*)wsb;     wsb += NTOK * D * 2;
    ushort* q    = (ushort*)wsb;     wsb += NTOK * D * 2;
    ushort* k    = (ushort*)wsb;     wsb += NTOK * D * 2;
    ushort* vT   = (ushort*)wsb;     wsb += NTOK * D * 2;
    ushort* u    = (ushort*)wsb;     wsb += NTOK * MLPD * 2;
    ushort* W1t  = (ushort*)wsb;     wsb += (size_t)NB * D * MLPD * 2;
    ushort* W2t  = (ushort*)wsb;     wsb += (size_t)NB * D * MLPD * 2;
    ushort* WqT  = (ushort*)wsb;     wsb += (size_t)NB * H * DH * DH * 2;
    ushort* WkT  = (ushort*)wsb;     wsb += (size_t)NB * H * DH * DH * 2;
    ushort* WvT  = (ushort*)wsb;     wsb += (size_t)NB * H * DH * DH * 2;
    ushort* srcb = (ushort*)wsb;     wsb += NTOK * F * 2;
    ushort* embWt= (ushort*)wsb;     wsb += (size_t)F * D * 2;

    // weight / input prep (every launch)
    wtrans_kernel<<<dim3(D / 32, MLPD / 32, NB), 256, 0, stream>>>(W1, W1t, D, MLPD);
    wtrans_kernel<<<dim3(MLPD / 32, D / 32, NB), 256, 0, stream>>>(W2, W2t, MLPD, D);
    wtransq_kernel<<<dim3(NB * H, 3), 256, 0, stream>>>(Wq, Wk, Wv, WqT, WkT, WvT);
    wtrans_kernel<<<dim3(F / 32, D / 32, 1), 256, 0, stream>>>(emb_W, embWt, F, D);
    castsrc_kernel<<<B * T, F, 0, stream>>>(src, srcb);

    embed_gemm<<<dim3(B * T / 128, D / 128), 256, 0, stream>>>(srcb, embWt, emb_b, cls_tok, x);

    for (int i = 0; i < NB; ++i) {
        ln_kernel<<<B * T / 4, 256, 0, stream>>>(x, ln1_g + i * D, ln1_b + i * D, hbuf);
        qkv_kernel<<<dim3(B * T / 128, H), 256, 0, stream>>>(hbuf,
            WqT + (size_t)i * H * DH * DH, bq + (size_t)i * H * DH,
            WkT + (size_t)i * H * DH * DH, bk + (size_t)i * H * DH,
            WvT + (size_t)i * H * DH * DH, bv + (size_t)i * H * DH,
            q, k, vT);
        attn_kernel<<<dim3(T / 64, B * H), 256, 0, stream>>>(q, k, vT, x);
        ln_kernel<<<B * T / 4, 256, 0, stream>>>(x, ln2_g + i * D, ln2_b + i * D, hbuf);
        mfma_gemm<0, 1><<<dim3(B * T / 128, MLPD / 128, 1), 256, 0, stream>>>(
            hbuf, W1t + (size_t)i * D * MLPD, b1 + (size_t)i * MLPD, u, B * T, MLPD, D);
        mfma_gemm<1, 2><<<dim3(B * T / 128, D / 128, 2), 256, 0, stream>>>(
            u, W2t + (size_t)i * MLPD * D, b2 + (size_t)i * D, x, B * T, D, MLPD);
    }

    head_kernel<<<B, 512, 0, stream>>>(x, head_W, head_b, (float*)d_out);
}